// Round 1
// baseline (1102.134 us; speedup 1.0000x reference)
//
#include <hip/hip_runtime.h>
#include <hip/hip_bf16.h>

// R-GCN 2-layer forward, restructured as: counting-sort edges by dst (once),
// per-node relation-bucketed aggregation ACC[v][r*128+i] = sum h[src], with
// self-loop in slot k=1024..1151, then bf16 MFMA GEMM [N,1152]@[1152,128]
// with fused bias+ReLU per layer.

#define D 128
#define RK 8
#define KTOT 1152   // 8*128 relations + 128 self-loop
#define BK 32

typedef __attribute__((ext_vector_type(8))) __bf16 bf16x8;
typedef __attribute__((ext_vector_type(8))) unsigned short us8;
typedef __attribute__((ext_vector_type(4))) float f32x4;

__device__ __forceinline__ unsigned short f2bf(float f) {
    union { float f; unsigned u; } v; v.f = f;
    unsigned r = v.u + 0x7FFF + ((v.u >> 16) & 1);   // RNE
    return (unsigned short)(r >> 16);
}

// LDS tile swizzle: 16 rows x 4 chunks of 8 bf16 (16B). chunk' = c ^ ((row>>1)&3)
// keeps 16B alignment and limits read conflicts to 2-way (free on gfx950).
__device__ __forceinline__ int lds_off(int row, int c) {
    return row * 32 + ((c ^ ((row >> 1) & 3)) << 3);
}

// ---------------- sort: histogram / scan / scatter ----------------

__global__ void hist_kernel(const int* __restrict__ dst, int* __restrict__ cnt, int E) {
    int e = blockIdx.x * blockDim.x + threadIdx.x;
    if (e < E) atomicAdd(&cnt[dst[e]], 1);
}

__global__ __launch_bounds__(1024) void scan_kernel(const int* __restrict__ cnt,
                                                    int* __restrict__ offs,
                                                    int* __restrict__ head, int N) {
    __shared__ int part[1024];
    int t = threadIdx.x;
    int chunk = (N + 1023) >> 10;
    int lo = t * chunk;
    int hi = lo + chunk; if (hi > N) hi = N;
    int sum = 0;
    for (int i = lo; i < hi; ++i) sum += cnt[i];
    part[t] = sum;
    __syncthreads();
    for (int off = 1; off < 1024; off <<= 1) {
        int vv = (t >= off) ? part[t - off] : 0;
        __syncthreads();
        part[t] += vv;
        __syncthreads();
    }
    int run = part[t] - sum;   // exclusive prefix of this thread's chunk
    for (int i = lo; i < hi; ++i) {
        offs[i] = run; head[i] = run;
        run += cnt[i];
    }
    if (t == 1023) offs[N] = run;   // last chunk is past N, run == total
}

__global__ void scatter_kernel(const int* __restrict__ src, const int* __restrict__ dst,
                               const int* __restrict__ et, int* __restrict__ head,
                               unsigned* __restrict__ sorted, int E) {
    int e = blockIdx.x * blockDim.x + threadIdx.x;
    if (e < E) {
        int d = dst[e];
        int pos = atomicAdd(&head[d], 1);
        sorted[pos] = ((unsigned)et[e] << 17) | (unsigned)src[e];   // src < 2^17
    }
}

// ---------------- weight cast: Bt[o][k] = W[k][o] in bf16 ----------------

__global__ void castB_kernel(const float* __restrict__ W1, const float* __restrict__ lw1,
                             const float* __restrict__ W2, const float* __restrict__ lw2,
                             unsigned short* __restrict__ Bt1, unsigned short* __restrict__ Bt2) {
    int idx = blockIdx.x * blockDim.x + threadIdx.x;
    const int per = KTOT * D;
    if (idx >= 2 * per) return;
    int layer = idx / per;
    int rem = idx - layer * per;
    int k = rem >> 7;        // 0..1151
    int o = rem & 127;       // coalesced read dimension
    const float* W  = layer ? W2 : W1;
    const float* lw = layer ? lw2 : lw1;
    // W[r][i][o] flat = (r*128+i)*128 + o = k*128 + o  for k < 1024
    float val = (k < 1024) ? W[k * D + o] : lw[(k - 1024) * D + o];
    unsigned short* Bt = layer ? Bt2 : Bt1;
    Bt[o * KTOT + k] = f2bf(val);
}

// ---------------- aggregation: ACC[v][r*128+i] = sum_{e in bucket} h[src][i] ----------------

__global__ __launch_bounds__(128) void aggregate_kernel(const float* __restrict__ h,
                                                        const int* __restrict__ offs,
                                                        const unsigned* __restrict__ sorted,
                                                        unsigned short* __restrict__ A) {
    int v = blockIdx.x;
    int tid = threadIdx.x;     // 0..127 — each thread owns one feature column
    __shared__ float acc[RK * D];
    #pragma unroll
    for (int r = 0; r < RK; ++r) acc[r * D + tid] = 0.f;
    // no barrier needed: each thread only ever touches column tid

    int e0 = offs[v], e1 = offs[v + 1];
    for (int e = e0; e < e1; ++e) {
        unsigned p = sorted[e];           // block-uniform
        int s = (int)(p & 131071u);
        int r = (int)(p >> 17);
        acc[r * D + tid] += h[(size_t)s * D + tid];
    }

    size_t base = (size_t)v * KTOT;
    #pragma unroll
    for (int r = 0; r < RK; ++r)
        A[base + r * D + tid] = f2bf(acc[r * D + tid]);
    A[base + 1024 + tid] = f2bf(h[(size_t)v * D + tid]);   // self-loop slot
}

// ---------------- GEMM: out[N][128] = ACC[N][1152] @ Bt^T + bias (+ReLU) ----------------

__global__ __launch_bounds__(256) void gemm_kernel(const unsigned short* __restrict__ A,
                                                   const unsigned short* __restrict__ Bt,
                                                   const float* __restrict__ bias,
                                                   float* __restrict__ out,
                                                   int N, int do_relu) {
    __shared__ unsigned short Alds[128 * 32];
    __shared__ unsigned short Blds[128 * 32];
    const int t = threadIdx.x;
    const int lane = t & 63;
    const int w = t >> 6;            // wave 0..3 -> rows w*32..w*32+31
    const int quad = lane >> 4;      // k-chunk for MFMA operands
    const int c16 = lane & 15;
    const int blockRow0 = blockIdx.x * 128;

    const int srow = t >> 2;         // staging: 0..63, 4 threads/row
    const int schunk = t & 3;

    f32x4 acc[2][8];
    #pragma unroll
    for (int i = 0; i < 2; ++i)
        #pragma unroll
        for (int j = 0; j < 8; ++j) acc[i][j] = f32x4{0.f, 0.f, 0.f, 0.f};

    const int aRow0 = blockRow0 + srow;
    const int aRow1 = blockRow0 + srow + 64;
    const bool val0 = aRow0 < N;
    const bool val1 = aRow1 < N;
    const us8 zz = {0, 0, 0, 0, 0, 0, 0, 0};

    for (int k0 = 0; k0 < KTOT; k0 += BK) {
        us8 av0 = zz, av1 = zz;
        if (val0) av0 = *(const us8*)(A + (size_t)aRow0 * KTOT + k0 + schunk * 8);
        if (val1) av1 = *(const us8*)(A + (size_t)aRow1 * KTOT + k0 + schunk * 8);
        us8 bv0 = *(const us8*)(Bt + (size_t)srow * KTOT + k0 + schunk * 8);
        us8 bv1 = *(const us8*)(Bt + (size_t)(srow + 64) * KTOT + k0 + schunk * 8);
        __syncthreads();   // previous iteration's reads done
        *(us8*)(Alds + lds_off(srow,      schunk)) = av0;
        *(us8*)(Alds + lds_off(srow + 64, schunk)) = av1;
        *(us8*)(Blds + lds_off(srow,      schunk)) = bv0;
        *(us8*)(Blds + lds_off(srow + 64, schunk)) = bv1;
        __syncthreads();

        bf16x8 af[2];
        #pragma unroll
        for (int rt = 0; rt < 2; ++rt)
            af[rt] = *(const bf16x8*)(Alds + lds_off(w * 32 + rt * 16 + c16, quad));
        #pragma unroll
        for (int ct = 0; ct < 8; ++ct) {
            bf16x8 bfr = *(const bf16x8*)(Blds + lds_off(ct * 16 + c16, quad));
            acc[0][ct] = __builtin_amdgcn_mfma_f32_16x16x32_bf16(af[0], bfr, acc[0][ct], 0, 0, 0);
            acc[1][ct] = __builtin_amdgcn_mfma_f32_16x16x32_bf16(af[1], bfr, acc[1][ct], 0, 0, 0);
        }
    }

    // epilogue: C[row=quad*4+i][col=c16] per 16x16 tile (m89-verified layout)
    #pragma unroll
    for (int rt = 0; rt < 2; ++rt) {
        int row = blockRow0 + w * 32 + rt * 16 + quad * 4;
        #pragma unroll
        for (int ct = 0; ct < 8; ++ct) {
            int col = ct * 16 + c16;
            float bcol = bias[col];
            #pragma unroll
            for (int i = 0; i < 4; ++i) {
                int r = row + i;
                if (r < N) {
                    float vv = acc[rt][ct][i] + bcol;
                    if (do_relu) vv = fmaxf(vv, 0.f);
                    out[(size_t)r * D + col] = vv;
                }
            }
        }
    }
}

// ---------------- launch ----------------

extern "C" void kernel_launch(void* const* d_in, const int* in_sizes, int n_in,
                              void* d_out, int out_size, void* d_ws, size_t ws_size,
                              hipStream_t stream) {
    const float* feats = (const float*)d_in[0];
    const float* W1    = (const float*)d_in[1];
    const float* lw1   = (const float*)d_in[2];
    const float* b1    = (const float*)d_in[3];
    const float* W2    = (const float*)d_in[4];
    const float* lw2   = (const float*)d_in[5];
    const float* b2    = (const float*)d_in[6];
    const int*   src   = (const int*)d_in[7];
    const int*   dst   = (const int*)d_in[8];
    const int*   etype = (const int*)d_in[9];
    const int N = in_sizes[0] / D;
    const int E = in_sizes[7];
    float* out = (float*)d_out;

    size_t woff = 0;
    auto take = [&](size_t bytes) -> void* {
        void* p = (char*)d_ws + woff;
        woff += (bytes + 255) & ~(size_t)255;
        return p;
    };
    int* cnt              = (int*)take((size_t)N * 4);
    int* offs             = (int*)take((size_t)(N + 1) * 4);
    int* head             = (int*)take((size_t)N * 4);
    unsigned* sorted      = (unsigned*)take((size_t)E * 4);
    unsigned short* Bt1   = (unsigned short*)take((size_t)KTOT * D * 2);
    unsigned short* Bt2   = (unsigned short*)take((size_t)KTOT * D * 2);
    unsigned short* ACC   = (unsigned short*)take((size_t)N * KTOT * 2);

    hipMemsetAsync(cnt, 0, (size_t)N * 4, stream);

    int eb = (E + 255) / 256;
    hist_kernel<<<eb, 256, 0, stream>>>(dst, cnt, E);
    scan_kernel<<<1, 1024, 0, stream>>>(cnt, offs, head, N);
    scatter_kernel<<<eb, 256, 0, stream>>>(src, dst, etype, head, sorted, E);

    int cb = (2 * KTOT * D + 255) / 256;
    castB_kernel<<<cb, 256, 0, stream>>>(W1, lw1, W2, lw2, Bt1, Bt2);

    int gb = (N + 127) / 128;

    // layer 1: feats -> d_out (h1)
    aggregate_kernel<<<N, 128, 0, stream>>>(feats, offs, sorted, ACC);
    gemm_kernel<<<gb, 256, 0, stream>>>(ACC, Bt1, b1, out, N, 1);

    // layer 2: h1 (in d_out) -> d_out
    aggregate_kernel<<<N, 128, 0, stream>>>(out, offs, sorted, ACC);
    gemm_kernel<<<gb, 256, 0, stream>>>(ACC, Bt2, b2, out, N, 0);
}

// Round 3
// 859.698 us; speedup vs baseline: 1.2820x; 1.2820x over previous
//
#include <hip/hip_runtime.h>
#include <hip/hip_bf16.h>

// R-GCN 2-layer forward: counting-sort edges by dst (hierarchical scan),
// wave-per-node relation-bucketed aggregation into bf16 ACC[N][1152]
// (slot 1024..1151 = self-loop h[v]), then bf16 MFMA GEMM [N,1152]@[1152,128]
// with fused bias+ReLU per layer.

#define D 128
#define RK 8
#define KTOT 1152   // 8*128 relations + 128 self-loop
#define BK 32

typedef __attribute__((ext_vector_type(8))) __bf16 bf16x8;
typedef __attribute__((ext_vector_type(8))) unsigned short us8;
typedef __attribute__((ext_vector_type(2))) unsigned short us2;
typedef __attribute__((ext_vector_type(4))) float f32x4;

__device__ __forceinline__ unsigned short f2bf(float f) {
    union { float f; unsigned u; } v; v.f = f;
    unsigned r = v.u + 0x7FFF + ((v.u >> 16) & 1);   // RNE
    return (unsigned short)(r >> 16);
}

__device__ __forceinline__ int lds_off(int row, int c) {
    return row * 32 + ((c ^ ((row >> 1) & 3)) << 3);
}

// ---------------- sort: histogram / hierarchical scan / scatter ----------------

__global__ void hist_kernel(const int* __restrict__ dst, int* __restrict__ cnt, int E) {
    int e = blockIdx.x * blockDim.x + threadIdx.x;
    if (e < E) atomicAdd(&cnt[dst[e]], 1);
}

// phase 1: per-block (1024 elems) sums
__global__ __launch_bounds__(256) void scan_partial(const int* __restrict__ cnt,
                                                    int* __restrict__ part, int N) {
    int t = threadIdx.x;
    int base = blockIdx.x * 1024 + t * 4;
    int4 v = {0, 0, 0, 0};
    if (base + 3 < N) v = *(const int4*)(cnt + base);
    else {
        if (base     < N) v.x = cnt[base];
        if (base + 1 < N) v.y = cnt[base + 1];
        if (base + 2 < N) v.z = cnt[base + 2];
        if (base + 3 < N) v.w = cnt[base + 3];
    }
    int s = v.x + v.y + v.z + v.w;
    #pragma unroll
    for (int off = 32; off; off >>= 1) s += __shfl_down(s, off, 64);
    __shared__ int ws[4];
    int lane = t & 63, w = t >> 6;
    if (lane == 0) ws[w] = s;
    __syncthreads();
    if (t == 0) part[blockIdx.x] = ws[0] + ws[1] + ws[2] + ws[3];
}

// phase 2: single small block scans the <=256 partials (exclusive), writes total
__global__ __launch_bounds__(256) void scan_root(int* __restrict__ part,
                                                 int* __restrict__ offs_total, int NB) {
    int t = threadIdx.x;
    int v = (t < NB) ? part[t] : 0;
    int lane = t & 63, w = t >> 6;
    int inc = v;
    #pragma unroll
    for (int off = 1; off < 64; off <<= 1) {
        int n = __shfl_up(inc, off, 64);
        if (lane >= off) inc += n;
    }
    __shared__ int ws[4];
    if (lane == 63) ws[w] = inc;
    __syncthreads();
    int wbase = 0;
    for (int i = 0; i < w; ++i) wbase += ws[i];
    if (t < NB) part[t] = wbase + inc - v;          // exclusive block base
    if (t == NB - 1) *offs_total = wbase + inc;     // offs[N] = E
}

// phase 3: per-block scan + global base -> offs/head
__global__ __launch_bounds__(256) void scan_final(const int* __restrict__ cnt,
                                                  const int* __restrict__ part,
                                                  int* __restrict__ offs,
                                                  int* __restrict__ head, int N) {
    int t = threadIdx.x;
    int base = blockIdx.x * 1024 + t * 4;
    int4 v = {0, 0, 0, 0};
    if (base + 3 < N) v = *(const int4*)(cnt + base);
    else {
        if (base     < N) v.x = cnt[base];
        if (base + 1 < N) v.y = cnt[base + 1];
        if (base + 2 < N) v.z = cnt[base + 2];
        if (base + 3 < N) v.w = cnt[base + 3];
    }
    int tsum = v.x + v.y + v.z + v.w;
    int lane = t & 63, w = t >> 6;
    int inc = tsum;
    #pragma unroll
    for (int off = 1; off < 64; off <<= 1) {
        int n = __shfl_up(inc, off, 64);
        if (lane >= off) inc += n;
    }
    __shared__ int ws[4];
    if (lane == 63) ws[w] = inc;
    __syncthreads();
    int wbase = 0;
    for (int i = 0; i < w; ++i) wbase += ws[i];
    int run = part[blockIdx.x] + wbase + inc - tsum;
    int4 o = {run, run + v.x, run + v.x + v.y, run + v.x + v.y + v.z};
    if (base + 3 < N) {
        *(int4*)(offs + base) = o;
        *(int4*)(head + base) = o;
    } else {
        if (base     < N) { offs[base]     = o.x; head[base]     = o.x; }
        if (base + 1 < N) { offs[base + 1] = o.y; head[base + 1] = o.y; }
        if (base + 2 < N) { offs[base + 2] = o.z; head[base + 2] = o.z; }
        if (base + 3 < N) { offs[base + 3] = o.w; head[base + 3] = o.w; }
    }
}

__global__ void scatter_kernel(const int* __restrict__ src, const int* __restrict__ dst,
                               const int* __restrict__ et, int* __restrict__ head,
                               unsigned* __restrict__ sorted, int E) {
    int e = blockIdx.x * blockDim.x + threadIdx.x;
    if (e < E) {
        int d = dst[e];
        int pos = atomicAdd(&head[d], 1);
        sorted[pos] = ((unsigned)et[e] << 17) | (unsigned)src[e];   // src < 2^17
    }
}

// ---------------- weight cast: Bt[o][k] = W[k][o] in bf16 ----------------

__global__ void castB_kernel(const float* __restrict__ W1, const float* __restrict__ lw1,
                             const float* __restrict__ W2, const float* __restrict__ lw2,
                             unsigned short* __restrict__ Bt1, unsigned short* __restrict__ Bt2) {
    int idx = blockIdx.x * blockDim.x + threadIdx.x;
    const int per = KTOT * D;
    if (idx >= 2 * per) return;
    int layer = idx / per;
    int rem = idx - layer * per;
    int k = rem >> 7;
    int o = rem & 127;
    const float* W  = layer ? W2 : W1;
    const float* lw = layer ? lw2 : lw1;
    float val = (k < 1024) ? W[k * D + o] : lw[(k - 1024) * D + o];
    unsigned short* Bt = layer ? Bt2 : Bt1;
    Bt[o * KTOT + k] = f2bf(val);
}

// ---------------- aggregation: wave-per-node, float2 per lane ----------------

__global__ __launch_bounds__(256) void aggregate_kernel(const float* __restrict__ h,
                                                        const int* __restrict__ offs,
                                                        const unsigned* __restrict__ sorted,
                                                        unsigned short* __restrict__ A,
                                                        int N) {
    int w = threadIdx.x >> 6;        // wave 0..3, one node each
    int lane = threadIdx.x & 63;     // lane owns cols 2*lane, 2*lane+1
    int v = blockIdx.x * 4 + w;
    __shared__ float accs[4][RK * D];    // 16 KB; per-wave region, no block barrier needed
    if (v >= N) return;
    float2* acc = (float2*)&accs[w][0];  // index r*64 + lane  (8B stride: free 2-way bank alias)
    #pragma unroll
    for (int r = 0; r < RK; ++r) acc[r * 64 + lane] = float2{0.f, 0.f};

    int e0 = offs[v], e1 = offs[v + 1];
    for (int e = e0; e < e1; ++e) {
        unsigned p = sorted[e];          // wave-uniform
        int s = (int)(p & 131071u);
        int r = (int)(p >> 17);
        float2 hv = *(const float2*)(h + (size_t)s * D + lane * 2);
        float2 a = acc[r * 64 + lane];
        a.x += hv.x; a.y += hv.y;
        acc[r * 64 + lane] = a;
    }

    size_t base = (size_t)v * KTOT;
    #pragma unroll
    for (int r = 0; r < RK; ++r) {
        float2 a = acc[r * 64 + lane];
        us2 o; o.x = f2bf(a.x); o.y = f2bf(a.y);
        *(us2*)(A + base + r * D + lane * 2) = o;
    }
    float2 hv = *(const float2*)(h + (size_t)v * D + lane * 2);   // self-loop slot
    us2 o; o.x = f2bf(hv.x); o.y = f2bf(hv.y);
    *(us2*)(A + base + 1024 + lane * 2) = o;
}

// ---------------- GEMM: out[N][128] = ACC[N][1152] @ Bt^T + bias (+ReLU) ----------------

__global__ __launch_bounds__(256) void gemm_kernel(const unsigned short* __restrict__ A,
                                                   const unsigned short* __restrict__ Bt,
                                                   const float* __restrict__ bias,
                                                   float* __restrict__ out,
                                                   int N, int do_relu) {
    __shared__ unsigned short Alds[128 * 32];
    __shared__ unsigned short Blds[128 * 32];
    const int t = threadIdx.x;
    const int lane = t & 63;
    const int w = t >> 6;
    const int quad = lane >> 4;
    const int c16 = lane & 15;
    const int blockRow0 = blockIdx.x * 128;

    const int srow = t >> 2;
    const int schunk = t & 3;

    f32x4 acc[2][8];
    #pragma unroll
    for (int i = 0; i < 2; ++i)
        #pragma unroll
        for (int j = 0; j < 8; ++j) acc[i][j] = f32x4{0.f, 0.f, 0.f, 0.f};

    const int aRow0 = blockRow0 + srow;
    const int aRow1 = blockRow0 + srow + 64;
    const bool val0 = aRow0 < N;
    const bool val1 = aRow1 < N;
    const us8 zz = {0, 0, 0, 0, 0, 0, 0, 0};

    for (int k0 = 0; k0 < KTOT; k0 += BK) {
        us8 av0 = zz, av1 = zz;
        if (val0) av0 = *(const us8*)(A + (size_t)aRow0 * KTOT + k0 + schunk * 8);
        if (val1) av1 = *(const us8*)(A + (size_t)aRow1 * KTOT + k0 + schunk * 8);
        us8 bv0 = *(const us8*)(Bt + (size_t)srow * KTOT + k0 + schunk * 8);
        us8 bv1 = *(const us8*)(Bt + (size_t)(srow + 64) * KTOT + k0 + schunk * 8);
        __syncthreads();
        *(us8*)(Alds + lds_off(srow,      schunk)) = av0;
        *(us8*)(Alds + lds_off(srow + 64, schunk)) = av1;
        *(us8*)(Blds + lds_off(srow,      schunk)) = bv0;
        *(us8*)(Blds + lds_off(srow + 64, schunk)) = bv1;
        __syncthreads();

        bf16x8 af[2];
        #pragma unroll
        for (int rt = 0; rt < 2; ++rt)
            af[rt] = *(const bf16x8*)(Alds + lds_off(w * 32 + rt * 16 + c16, quad));
        #pragma unroll
        for (int ct = 0; ct < 8; ++ct) {
            bf16x8 bfr = *(const bf16x8*)(Blds + lds_off(ct * 16 + c16, quad));
            acc[0][ct] = __builtin_amdgcn_mfma_f32_16x16x32_bf16(af[0], bfr, acc[0][ct], 0, 0, 0);
            acc[1][ct] = __builtin_amdgcn_mfma_f32_16x16x32_bf16(af[1], bfr, acc[1][ct], 0, 0, 0);
        }
    }

    #pragma unroll
    for (int rt = 0; rt < 2; ++rt) {
        int row = blockRow0 + w * 32 + rt * 16 + quad * 4;
        #pragma unroll
        for (int ct = 0; ct < 8; ++ct) {
            int col = ct * 16 + c16;
            float bcol = bias[col];
            #pragma unroll
            for (int i = 0; i < 4; ++i) {
                int r = row + i;
                if (r < N) {
                    float vv = acc[rt][ct][i] + bcol;
                    if (do_relu) vv = fmaxf(vv, 0.f);
                    out[(size_t)r * D + col] = vv;
                }
            }
        }
    }
}

// ---------------- launch ----------------

extern "C" void kernel_launch(void* const* d_in, const int* in_sizes, int n_in,
                              void* d_out, int out_size, void* d_ws, size_t ws_size,
                              hipStream_t stream) {
    const float* feats = (const float*)d_in[0];
    const float* W1    = (const float*)d_in[1];
    const float* lw1   = (const float*)d_in[2];
    const float* b1    = (const float*)d_in[3];
    const float* W2    = (const float*)d_in[4];
    const float* lw2   = (const float*)d_in[5];
    const float* b2    = (const float*)d_in[6];
    const int*   src   = (const int*)d_in[7];
    const int*   dst   = (const int*)d_in[8];
    const int*   etype = (const int*)d_in[9];
    const int N = in_sizes[0] / D;
    const int E = in_sizes[7];
    float* out = (float*)d_out;

    size_t woff = 0;
    auto take = [&](size_t bytes) -> void* {
        void* p = (char*)d_ws + woff;
        woff += (bytes + 255) & ~(size_t)255;
        return p;
    };
    int* cnt              = (int*)take((size_t)N * 4);
    int* offs             = (int*)take((size_t)(N + 1) * 4);
    int* head             = (int*)take((size_t)N * 4);
    int* part             = (int*)take((size_t)256 * 4);
    unsigned* sorted      = (unsigned*)take((size_t)E * 4);
    unsigned short* Bt1   = (unsigned short*)take((size_t)KTOT * D * 2);
    unsigned short* Bt2   = (unsigned short*)take((size_t)KTOT * D * 2);
    unsigned short* ACC   = (unsigned short*)take((size_t)N * KTOT * 2);

    (void)hipMemsetAsync(cnt, 0, (size_t)N * 4, stream);

    int eb = (E + 255) / 256;
    hist_kernel<<<eb, 256, 0, stream>>>(dst, cnt, E);

    int NB = (N + 1023) / 1024;        // 98 <= 256
    scan_partial<<<NB, 256, 0, stream>>>(cnt, part, N);
    scan_root<<<1, 256, 0, stream>>>(part, offs + N, NB);
    scan_final<<<NB, 256, 0, stream>>>(cnt, part, offs, head, N);

    scatter_kernel<<<eb, 256, 0, stream>>>(src, dst, etype, head, sorted, E);

    int cb = (2 * KTOT * D + 255) / 256;
    castB_kernel<<<cb, 256, 0, stream>>>(W1, lw1, W2, lw2, Bt1, Bt2);

    int gb = (N + 127) / 128;
    int ab = (N + 3) / 4;

    // layer 1: feats -> d_out (h1)
    aggregate_kernel<<<ab, 256, 0, stream>>>(feats, offs, sorted, ACC, N);
    gemm_kernel<<<gb, 256, 0, stream>>>(ACC, Bt1, b1, out, N, 1);

    // layer 2: h1 (in d_out) -> d_out
    aggregate_kernel<<<ab, 256, 0, stream>>>(out, offs, sorted, ACC, N);
    gemm_kernel<<<gb, 256, 0, stream>>>(ACC, Bt2, b2, out, N, 0);
}